// Round 2
// baseline (640.082 us; speedup 1.0000x reference)
//
#include <hip/hip_runtime.h>
#include <math.h>

#define NB 8
#define NS 4
#define NP 4096
#define HID 4096
#define NHQ 32
#define NHKV 8
#define ND 128
#define NGROUP 4
#define NBS 32      /* NB*NS rows */
#define NQI 16      /* NGROUP*NS q-rows per (b,kv) */
#define NCHUNK 17   /* 16 cache chunks of 256 + 1 new-token chunk */
#define TCHUNK 256
#define KSPLIT 16
#define QKV_COLS 6144
#define LOG2E 1.4426950408889634f

// ---------------- transpose x (32 x 4096) -> xT (4096 x 32) ----------------
__global__ __launch_bounds__(256) void prep_xT(const float* __restrict__ x,
                                               float* __restrict__ xT) {
  int n = blockIdx.x * 256 + threadIdx.x;  // n < 131072
  int r = n >> 12;
  int k = n & 4095;
  xT[k * NBS + r] = x[n];
}

// ---------------- RoPE: q -> q_t[(b,kv)][d][i], k_new -> [(b,kv)][s][d] ----
__global__ __launch_bounds__(256) void rope_kernel(
    const float* __restrict__ qb, const float* __restrict__ kb,
    const float* __restrict__ cosp, const float* __restrict__ sinp,
    const int* __restrict__ past_len, float* __restrict__ q_t,
    float* __restrict__ k_new) {
  int n = blockIdx.x * 256 + threadIdx.x;
  int pl = past_len[0];
  if (n < NBS * HID) {  // q element
    int r = n >> 12;    // b*4+s
    int hd = n & 4095;
    int h = hd >> 7, d = hd & 127;
    int b = r >> 2, s = r & 3;
    int pos = pl + s;
    float c = cosp[pos * ND + d], sn = sinp[pos * ND + d];
    float v = qb[n];
    float other = (d < 64) ? -qb[n + 64] : qb[n - 64];
    float rv = fmaf(v, c, other * sn);
    int kv = h >> 2, g = h & 3;
    q_t[(((b * NHKV + kv) * ND + d) * NQI) + g * NS + s] = rv;
  } else {  // k element
    n -= NBS * HID;  // n < 32768
    int r = n >> 10;
    int hd = n & 1023;
    int kv = hd >> 7, d = hd & 127;
    int b = r >> 2, s = r & 3;
    int pos = pl + s;
    float c = cosp[pos * ND + d], sn = sinp[pos * ND + d];
    float v = kb[n];
    float other = (d < 64) ? -kb[n + 64] : kb[n - 64];
    k_new[((b * NHKV + kv) * NS + s) * ND + d] = fmaf(v, c, other * sn);
  }
}

// -------- GEMM partials: P[kb][32][ncols] = A_T-slice x W-slice ------------
// mode 0: fused qkv col space 6144 (wq | wk | wv). mode 1: wo (4096 cols).
// block: 256 thr = 4 waves, each wave a 64-k slice; lanes cover 128 cols
// via float2. Cross-wave sum via LDS tree, wave 0 stores the partial.
__global__ __launch_bounds__(256) void gemm_part(
    const float* __restrict__ A_T, const float* __restrict__ wq,
    const float* __restrict__ wk, const float* __restrict__ wv,
    const float* __restrict__ wo, float* __restrict__ P, int mode) {
  __shared__ float lds[2 * 64 * 64];  // 32 KB
  int cb = blockIdx.x, kb = blockIdx.y;
  int ncols = mode ? 4096 : QKV_COLS;
  int col0 = cb * 128;
  const float* W;
  int ld, wcol;
  if (mode) {
    W = wo; ld = 4096; wcol = col0;
  } else if (col0 < 4096) {
    W = wq; ld = 4096; wcol = col0;
  } else if (col0 < 5120) {
    W = wk; ld = 1024; wcol = col0 - 4096;
  } else {
    W = wv; ld = 1024; wcol = col0 - 5120;
  }
  int tid = threadIdx.x;
  int lane = tid & 63;
  int wid = __builtin_amdgcn_readfirstlane(tid >> 6);
  int k0 = kb * 256 + wid * 64;
  const float* wp = W + (size_t)k0 * ld + wcol + lane * 2;
  const float* xp = A_T + (size_t)k0 * NBS;
  float acc[64];
#pragma unroll
  for (int v = 0; v < 64; v++) acc[v] = 0.f;
#pragma unroll 2
  for (int kk = 0; kk < 64; ++kk) {
    float2 w2 = *(const float2*)(wp + (size_t)kk * ld);
    const float* xr = xp + kk * NBS;  // wave-uniform -> s_load
#pragma unroll
    for (int m = 0; m < NBS; m++) {
      acc[2 * m] = fmaf(xr[m], w2.x, acc[2 * m]);
      acc[2 * m + 1] = fmaf(xr[m], w2.y, acc[2 * m + 1]);
    }
  }
  if (wid >= 2) {
#pragma unroll
    for (int v = 0; v < 64; v++) lds[(wid - 2) * 4096 + v * 64 + lane] = acc[v];
  }
  __syncthreads();
  if (wid < 2) {
#pragma unroll
    for (int v = 0; v < 64; v++) acc[v] += lds[wid * 4096 + v * 64 + lane];
  }
  __syncthreads();
  if (wid == 1) {
#pragma unroll
    for (int v = 0; v < 64; v++) lds[v * 64 + lane] = acc[v];
  }
  __syncthreads();
  if (wid == 0) {
#pragma unroll
    for (int v = 0; v < 64; v++) acc[v] += lds[v * 64 + lane];
#pragma unroll
    for (int m = 0; m < NBS; m++) {
      float2 st = make_float2(acc[2 * m], acc[2 * m + 1]);
      *(float2*)(P + ((size_t)kb * NBS + m) * ncols + col0 + lane * 2) = st;
    }
  }
}

// ---------------- reduce partials: qkv -> qb/kb/vb -------------------------
__global__ __launch_bounds__(256) void reduce_qkv(const float* __restrict__ P,
                                                  float* __restrict__ qb,
                                                  float* __restrict__ kbuf,
                                                  float* __restrict__ vbuf) {
  size_t idx = ((size_t)blockIdx.x * 256 + threadIdx.x) * 4;  // < 196608
  float4 s = make_float4(0.f, 0.f, 0.f, 0.f);
#pragma unroll
  for (int p = 0; p < KSPLIT; p++) {
    float4 v = *(const float4*)(P + (size_t)p * (NBS * QKV_COLS) + idx);
    s.x += v.x; s.y += v.y; s.z += v.z; s.w += v.w;
  }
  int r = (int)(idx / QKV_COLS);
  int col = (int)(idx % QKV_COLS);
  float* dst;
  if (col < 4096)
    dst = qb + (size_t)r * 4096 + col;
  else if (col < 5120)
    dst = kbuf + (size_t)r * 1024 + (col - 4096);
  else
    dst = vbuf + (size_t)r * 1024 + (col - 5120);
  *(float4*)dst = s;
}

// ---------------- reduce partials: out-proj -> out -------------------------
__global__ __launch_bounds__(256) void reduce_o(const float* __restrict__ P,
                                                float* __restrict__ outp) {
  size_t idx = ((size_t)blockIdx.x * 256 + threadIdx.x) * 4;  // < 131072
  float4 s = make_float4(0.f, 0.f, 0.f, 0.f);
#pragma unroll
  for (int p = 0; p < KSPLIT; p++) {
    float4 v = *(const float4*)(P + (size_t)p * (NBS * 4096) + idx);
    s.x += v.x; s.y += v.y; s.z += v.z; s.w += v.w;
  }
  *(float4*)(outp + idx) = s;
}

// ---------------- attention: grid = bk*17 + chunk, 512 threads -------------
__global__ __launch_bounds__(512, 6) void attn_kernel(
    const float* __restrict__ q_t, const float* __restrict__ k_cache,
    const float* __restrict__ v_cache, const float* __restrict__ k_new,
    const float* __restrict__ vbuf, float* __restrict__ part_o,
    float* __restrict__ part_m, float* __restrict__ part_l) {
  __shared__ float p_lds[TCHUNK * 17];  // stride 17: conflict-free
  __shared__ float redm[NQI][8];
  __shared__ float redl[NQI][8];
  __shared__ float mfin[NQI];
  int blk = blockIdx.x;
  int chunk = blk % NCHUNK;
  int bk = blk / NCHUNK;
  int b = bk >> 3, kv = bk & 7;
  int tid = threadIdx.x;
  int lane = tid & 63;
  int wid = tid >> 6;
  bool last = (chunk == NCHUNK - 1);
  int tcount = last ? NS : TCHUNK;
  const float* qbase = q_t + (size_t)bk * (ND * NQI);

  // ---- scores: 2 threads per t, each half of d ----
  int t_loc = tid >> 1;
  int half = tid & 1;
  bool valid = t_loc < tcount;
  int t_eff = valid ? t_loc : 0;
  const float* kp =
      last ? (k_new + ((size_t)bk * NS + t_eff) * ND + half * 64)
           : (k_cache +
              (((size_t)b * NP + chunk * TCHUNK + t_eff) * NHKV + kv) * ND +
              half * 64);
  float s_acc[NQI];
#pragma unroll
  for (int i = 0; i < NQI; i++) s_acc[i] = 0.f;
#pragma unroll 4
  for (int d4 = 0; d4 < 16; ++d4) {
    float4 kvv = *(const float4*)(kp + d4 * 4);
    const float* qp = qbase + (half * 64 + d4 * 4) * NQI;  // uniform s_load
#pragma unroll
    for (int i = 0; i < NQI; i++) {
      float s = s_acc[i];
      s = fmaf(kvv.x, qp[i], s);
      s = fmaf(kvv.y, qp[NQI + i], s);
      s = fmaf(kvv.z, qp[2 * NQI + i], s);
      s = fmaf(kvv.w, qp[3 * NQI + i], s);
      s_acc[i] = s;
    }
  }
  const float scale = 0.08838834764831845f;  // 1/sqrt(128)
  float sc[NQI];
#pragma unroll
  for (int i = 0; i < NQI; i++) {
    float s = s_acc[i] + __shfl_xor(s_acc[i], 1, 64);  // combine d-halves
    s *= scale;
    if (!valid || (last && t_loc > (i & 3))) s = -__builtin_inff();
    sc[i] = s;
  }
  // wave max per i -> LDS
#pragma unroll
  for (int i = 0; i < NQI; i++) {
    float m = sc[i];
#pragma unroll
    for (int off = 1; off < 64; off <<= 1) m = fmaxf(m, __shfl_xor(m, off, 64));
    if (lane == 0) redm[i][wid] = m;
  }
  __syncthreads();
  if (tid < NQI) {
    float m = redm[tid][0];
#pragma unroll
    for (int w = 1; w < 8; w++) m = fmaxf(m, redm[tid][w]);
    mfin[tid] = m;
  }
  __syncthreads();
#pragma unroll
  for (int i = 0; i < NQI; i++) {
    float p = exp2f((sc[i] - mfin[i]) * LOG2E);
    if (half == 0) p_lds[t_loc * 17 + i] = p;
    float lp = (half == 0) ? p : 0.f;
#pragma unroll
    for (int off = 1; off < 64; off <<= 1) lp += __shfl_xor(lp, off, 64);
    if (lane == 0) redl[i][wid] = lp;
  }
  __syncthreads();
  if (tid < NQI) {
    float l = redl[tid][0];
#pragma unroll
    for (int w = 1; w < 8; w++) l += redl[tid][w];
    part_m[(size_t)blk * NQI + tid] = mfin[tid];
    part_l[(size_t)blk * NQI + tid] = l;
  }

  // ---- PV: thread -> 1 q-row x 4 d ----
  int i0 = tid >> 5;
  int dq = (tid & 31) * 4;
  const float* vpb =
      last ? (vbuf + (size_t)b * NS * (NHKV * ND) + kv * ND + dq)
           : (v_cache + ((size_t)b * NP + chunk * TCHUNK) * (NHKV * ND) +
              kv * ND + dq);
  float o0 = 0.f, o1 = 0.f, o2 = 0.f, o3 = 0.f;
#pragma unroll 4
  for (int t = 0; t < tcount; ++t) {
    float4 vv = *(const float4*)(vpb + (size_t)t * (NHKV * ND));
    float p = p_lds[t * 17 + i0];
    o0 = fmaf(p, vv.x, o0);
    o1 = fmaf(p, vv.y, o1);
    o2 = fmaf(p, vv.z, o2);
    o3 = fmaf(p, vv.w, o3);
  }
  float4 st = make_float4(o0, o1, o2, o3);
  *(float4*)(part_o + (size_t)blk * (NQI * ND) + (size_t)i0 * ND + dq) = st;
}

// ---------------- combine partials -> attn_T (4096 x 32) -------------------
__global__ __launch_bounds__(256) void combine_kernel(
    const float* __restrict__ part_o, const float* __restrict__ part_m,
    const float* __restrict__ part_l, float* __restrict__ attn_T) {
  int bk = blockIdx.x;
  int tid = threadIdx.x;
  int i = tid >> 4;
  int dh = (tid & 15) * 4 + blockIdx.y * 64;
  float M = -__builtin_inff();
#pragma unroll
  for (int c = 0; c < NCHUNK; c++)
    M = fmaxf(M, part_m[((size_t)bk * NCHUNK + c) * NQI + i]);
  float L = 0.f;
  float o0 = 0.f, o1 = 0.f, o2 = 0.f, o3 = 0.f;
#pragma unroll
  for (int c = 0; c < NCHUNK; c++) {
    size_t pc = (size_t)bk * NCHUNK + c;
    float mc = part_m[pc * NQI + i];
    float w = exp2f((mc - M) * LOG2E);
    L = fmaf(part_l[pc * NQI + i], w, L);
    float4 po = *(const float4*)(part_o + pc * (NQI * ND) + (size_t)i * ND + dh);
    o0 = fmaf(w, po.x, o0);
    o1 = fmaf(w, po.y, o1);
    o2 = fmaf(w, po.z, o2);
    o3 = fmaf(w, po.w, o3);
  }
  float inv = 1.0f / L;
  int b = bk >> 3, kv = bk & 7;
  int g = i >> 2, s = i & 3;
  int h = kv * NGROUP + g;
  int r = b * NS + s;
  attn_T[(size_t)(h * ND + dh + 0) * NBS + r] = o0 * inv;
  attn_T[(size_t)(h * ND + dh + 1) * NBS + r] = o1 * inv;
  attn_T[(size_t)(h * ND + dh + 2) * NBS + r] = o2 * inv;
  attn_T[(size_t)(h * ND + dh + 3) * NBS + r] = o3 * inv;
}

// ---------------------------------------------------------------------------
extern "C" void kernel_launch(void* const* d_in, const int* in_sizes, int n_in,
                              void* d_out, int out_size, void* d_ws,
                              size_t ws_size, hipStream_t stream) {
  const float* x = (const float*)d_in[0];
  const float* wq = (const float*)d_in[1];
  const float* wk = (const float*)d_in[2];
  const float* wv = (const float*)d_in[3];
  const float* wo = (const float*)d_in[4];
  const float* cosp = (const float*)d_in[5];
  const float* sinp = (const float*)d_in[6];
  const float* k_cache = (const float*)d_in[7];
  const float* v_cache = (const float*)d_in[8];
  const int* past_len = (const int*)d_in[9];
  float* out = (float*)d_out;

  float* ws = (float*)d_ws;
  float* xT = ws;                   // 131072
  float* qb = xT + 131072;          // 131072
  float* kbuf = qb + 131072;        // 32768
  float* vbuf = kbuf + 32768;       // 32768
  float* q_t = vbuf + 32768;        // 131072
  float* k_new = q_t + 131072;      // 32768
  float* attn_T = k_new + 32768;    // 131072
  float* R = attn_T + 131072;       // shared region, 3145728 floats
  float* Pq = R;                    // 16*32*6144 = 3145728 (dead after reduce_qkv)
  float* part_o = R;                // 64*17*2048 = 2228224 (dead after combine)
  float* part_m = R + 2228224;      // 17408
  float* part_l = part_m + 17408;   // 17408
  float* Po = R;                    // 16*32*4096 = 2097152

  prep_xT<<<512, 256, 0, stream>>>(x, xT);
  gemm_part<<<dim3(48, KSPLIT), 256, 0, stream>>>(xT, wq, wk, wv, wo, Pq, 0);
  reduce_qkv<<<192, 256, 0, stream>>>(Pq, qb, kbuf, vbuf);
  rope_kernel<<<640, 256, 0, stream>>>(qb, kbuf, cosp, sinp, past_len, q_t,
                                       k_new);
  attn_kernel<<<64 * NCHUNK, 512, 0, stream>>>(q_t, k_cache, v_cache, k_new,
                                               vbuf, part_o, part_m, part_l);
  combine_kernel<<<dim3(64, 2), 256, 0, stream>>>(part_o, part_m, part_l,
                                                  attn_T);
  gemm_part<<<dim3(32, KSPLIT), 256, 0, stream>>>(attn_T, wq, wk, wv, wo, Po,
                                                  1);
  reduce_o<<<128, 256, 0, stream>>>(Po, out);
}

// Round 3
// 462.920 us; speedup vs baseline: 1.3827x; 1.3827x over previous
//
#include <hip/hip_runtime.h>
#include <math.h>

#define NB 8
#define NS 4
#define NP 4096
#define HID 4096
#define NHQ 32
#define NHKV 8
#define ND 128
#define NGROUP 4
#define NBS 32      /* NB*NS rows */
#define NQI 16      /* NGROUP*NS q-rows per (b,kv) */
#define NCHUNK 17   /* 16 cache chunks of 256 + 1 new-token chunk */
#define TCHUNK 256
#define KSPLIT 16
#define QKV_COLS 6144
#define LOG2E 1.4426950408889634f

// ---------------- transpose x (32 x 4096) -> xT (4096 x 32) ----------------
__global__ __launch_bounds__(256) void prep_xT(const float* __restrict__ x,
                                               float* __restrict__ xT) {
  int n = blockIdx.x * 256 + threadIdx.x;  // n < 131072
  int r = n >> 12;
  int k = n & 4095;
  xT[k * NBS + r] = x[n];
}

// ---------------- RoPE: q -> q_t[(b,kv)][d][i], k_new -> [(b,kv)][s][d] ----
__global__ __launch_bounds__(256) void rope_kernel(
    const float* __restrict__ qb, const float* __restrict__ kb,
    const float* __restrict__ cosp, const float* __restrict__ sinp,
    const int* __restrict__ past_len, float* __restrict__ q_t,
    float* __restrict__ k_new) {
  int n = blockIdx.x * 256 + threadIdx.x;
  int pl = past_len[0];
  if (n < NBS * HID) {  // q element
    int r = n >> 12;    // b*4+s
    int hd = n & 4095;
    int h = hd >> 7, d = hd & 127;
    int b = r >> 2, s = r & 3;
    int pos = pl + s;
    float c = cosp[pos * ND + d], sn = sinp[pos * ND + d];
    float v = qb[n];
    float other = (d < 64) ? -qb[n + 64] : qb[n - 64];
    float rv = fmaf(v, c, other * sn);
    int kv = h >> 2, g = h & 3;
    q_t[(((b * NHKV + kv) * ND + d) * NQI) + g * NS + s] = rv;
  } else {  // k element
    n -= NBS * HID;  // n < 32768
    int r = n >> 10;
    int hd = n & 1023;
    int kv = hd >> 7, d = hd & 127;
    int b = r >> 2, s = r & 3;
    int pos = pl + s;
    float c = cosp[pos * ND + d], sn = sinp[pos * ND + d];
    float v = kb[n];
    float other = (d < 64) ? -kb[n + 64] : kb[n - 64];
    k_new[((b * NHKV + kv) * NS + s) * ND + d] = fmaf(v, c, other * sn);
  }
}

// -------- GEMM partials: P[kb][32][ncols] = A_T-slice x W-slice ------------
// block: 256 thr = 4 waves, each wave a 64-k slice; lanes cover 128 cols via
// float2. Software-pipelined: 8 W-loads always in flight. LDS tree-reduce.
__global__ __launch_bounds__(256) void gemm_part(
    const float* __restrict__ A_T, const float* __restrict__ wq,
    const float* __restrict__ wk, const float* __restrict__ wv,
    const float* __restrict__ wo, float* __restrict__ P, int mode) {
  __shared__ float lds[2 * 64 * 64];  // 32 KB
  int cb = blockIdx.x, kb = blockIdx.y;
  int ncols = mode ? 4096 : QKV_COLS;
  int col0 = cb * 128;
  const float* W;
  int ld, wcol;
  if (mode) {
    W = wo; ld = 4096; wcol = col0;
  } else if (col0 < 4096) {
    W = wq; ld = 4096; wcol = col0;
  } else if (col0 < 5120) {
    W = wk; ld = 1024; wcol = col0 - 4096;
  } else {
    W = wv; ld = 1024; wcol = col0 - 5120;
  }
  int tid = threadIdx.x;
  int lane = tid & 63;
  int wid = __builtin_amdgcn_readfirstlane(tid >> 6);
  int k0 = kb * 256 + wid * 64;
  const float* wp = W + (size_t)k0 * ld + wcol + lane * 2;
  const float* xp = A_T + (size_t)k0 * NBS;
  float acc[64];
#pragma unroll
  for (int v = 0; v < 64; v++) acc[v] = 0.f;

  float2 wbuf[8];
#pragma unroll
  for (int u = 0; u < 8; u++) wbuf[u] = *(const float2*)(wp + (size_t)u * ld);
#pragma unroll 1
  for (int kk = 0; kk < 64; kk += 8) {
    float2 cur[8];
#pragma unroll
    for (int u = 0; u < 8; u++) cur[u] = wbuf[u];
    if (kk + 8 < 64) {
#pragma unroll
      for (int u = 0; u < 8; u++)
        wbuf[u] = *(const float2*)(wp + (size_t)(kk + 8 + u) * ld);
    }
#pragma unroll
    for (int u = 0; u < 8; u++) {
      const float* xr = xp + (kk + u) * NBS;  // wave-uniform -> s_load
#pragma unroll
      for (int m = 0; m < NBS; m++) {
        acc[2 * m] = fmaf(xr[m], cur[u].x, acc[2 * m]);
        acc[2 * m + 1] = fmaf(xr[m], cur[u].y, acc[2 * m + 1]);
      }
    }
  }
  if (wid >= 2) {
#pragma unroll
    for (int v = 0; v < 64; v++) lds[(wid - 2) * 4096 + v * 64 + lane] = acc[v];
  }
  __syncthreads();
  if (wid < 2) {
#pragma unroll
    for (int v = 0; v < 64; v++) acc[v] += lds[wid * 4096 + v * 64 + lane];
  }
  __syncthreads();
  if (wid == 1) {
#pragma unroll
    for (int v = 0; v < 64; v++) lds[v * 64 + lane] = acc[v];
  }
  __syncthreads();
  if (wid == 0) {
#pragma unroll
    for (int v = 0; v < 64; v++) acc[v] += lds[v * 64 + lane];
#pragma unroll
    for (int m = 0; m < NBS; m++) {
      float2 st = make_float2(acc[2 * m], acc[2 * m + 1]);
      *(float2*)(P + ((size_t)kb * NBS + m) * ncols + col0 + lane * 2) = st;
    }
  }
}

// ---------------- reduce partials: qkv -> qb/kb/vb -------------------------
__global__ __launch_bounds__(256) void reduce_qkv(const float* __restrict__ P,
                                                  float* __restrict__ qb,
                                                  float* __restrict__ kbuf,
                                                  float* __restrict__ vbuf) {
  size_t idx = ((size_t)blockIdx.x * 256 + threadIdx.x) * 4;  // < 196608
  float4 s = make_float4(0.f, 0.f, 0.f, 0.f);
#pragma unroll
  for (int p = 0; p < KSPLIT; p++) {
    float4 v = *(const float4*)(P + (size_t)p * (NBS * QKV_COLS) + idx);
    s.x += v.x; s.y += v.y; s.z += v.z; s.w += v.w;
  }
  int r = (int)(idx / QKV_COLS);
  int col = (int)(idx % QKV_COLS);
  float* dst;
  if (col < 4096)
    dst = qb + (size_t)r * 4096 + col;
  else if (col < 5120)
    dst = kbuf + (size_t)r * 1024 + (col - 4096);
  else
    dst = vbuf + (size_t)r * 1024 + (col - 5120);
  *(float4*)dst = s;
}

// ---------------- reduce partials: out-proj -> out -------------------------
__global__ __launch_bounds__(256) void reduce_o(const float* __restrict__ P,
                                                float* __restrict__ outp) {
  size_t idx = ((size_t)blockIdx.x * 256 + threadIdx.x) * 4;  // < 131072
  float4 s = make_float4(0.f, 0.f, 0.f, 0.f);
#pragma unroll
  for (int p = 0; p < KSPLIT; p++) {
    float4 v = *(const float4*)(P + (size_t)p * (NBS * 4096) + idx);
    s.x += v.x; s.y += v.y; s.z += v.z; s.w += v.w;
  }
  *(float4*)(outp + idx) = s;
}

// ---------------- attention: grid = (bk, chunk), 256 threads ---------------
__global__ __launch_bounds__(256) void attn_kernel(
    const float* __restrict__ q_t, const float* __restrict__ k_cache,
    const float* __restrict__ v_cache, const float* __restrict__ k_new,
    const float* __restrict__ vbuf, float* __restrict__ part_o,
    float* __restrict__ part_m, float* __restrict__ part_l) {
  __shared__ float p_lds[TCHUNK * 17];  // stride 17: conflict-free
  __shared__ float redm[NQI][4];
  __shared__ float redl[NQI][4];
  __shared__ float mfin[NQI];
  int bk = blockIdx.x;
  int chunk = blockIdx.y;
  int blk = bk * NCHUNK + chunk;
  int b = bk >> 3, kv = bk & 7;
  int tid = threadIdx.x;
  int lane = tid & 63;
  int wid = tid >> 6;
  bool last = (chunk == NCHUNK - 1);
  int tcount = last ? NS : TCHUNK;
  const float* qbase = q_t + (size_t)bk * (ND * NQI);

  // ---- scores: one thread per t, full d (per-lane sequential streaming) ---
  int t_loc = tid;
  bool valid = t_loc < tcount;
  int t_eff = valid ? t_loc : 0;
  const float* kp =
      last ? (k_new + ((size_t)bk * NS + t_eff) * ND)
           : (k_cache +
              (((size_t)b * NP + chunk * TCHUNK + t_eff) * NHKV + kv) * ND);
  float s_acc[NQI];
#pragma unroll
  for (int i = 0; i < NQI; i++) s_acc[i] = 0.f;
#pragma unroll 8
  for (int d4 = 0; d4 < 32; ++d4) {
    float4 kvv = *(const float4*)(kp + d4 * 4);
    const float* qp = qbase + (d4 * 4) * NQI;  // uniform -> s_load
#pragma unroll
    for (int i = 0; i < NQI; i++) {
      float s = s_acc[i];
      s = fmaf(kvv.x, qp[i], s);
      s = fmaf(kvv.y, qp[NQI + i], s);
      s = fmaf(kvv.z, qp[2 * NQI + i], s);
      s = fmaf(kvv.w, qp[3 * NQI + i], s);
      s_acc[i] = s;
    }
  }
  const float scale = 0.08838834764831845f;  // 1/sqrt(128)
  float sc[NQI];
#pragma unroll
  for (int i = 0; i < NQI; i++) {
    float s = s_acc[i] * scale;
    if (!valid || (last && t_loc > (i & 3))) s = -__builtin_inff();
    sc[i] = s;
  }
  // wave max per i -> LDS
#pragma unroll
  for (int i = 0; i < NQI; i++) {
    float m = sc[i];
#pragma unroll
    for (int off = 1; off < 64; off <<= 1) m = fmaxf(m, __shfl_xor(m, off, 64));
    if (lane == 0) redm[i][wid] = m;
  }
  __syncthreads();
  if (tid < NQI) {
    float m = fmaxf(fmaxf(redm[tid][0], redm[tid][1]),
                    fmaxf(redm[tid][2], redm[tid][3]));
    mfin[tid] = m;
  }
  __syncthreads();
  float l_loc[NQI];
#pragma unroll
  for (int i = 0; i < NQI; i++) {
    float p = exp2f((sc[i] - mfin[i]) * LOG2E);
    p_lds[t_loc * 17 + i] = p;
    l_loc[i] = p;
  }
#pragma unroll
  for (int i = 0; i < NQI; i++) {
    float l = l_loc[i];
#pragma unroll
    for (int off = 1; off < 64; off <<= 1) l += __shfl_xor(l, off, 64);
    if (lane == 0) redl[i][wid] = l;
  }
  __syncthreads();
  if (tid < NQI) {
    float l = redl[tid][0] + redl[tid][1] + redl[tid][2] + redl[tid][3];
    part_m[(size_t)blk * NQI + tid] = mfin[tid];
    part_l[(size_t)blk * NQI + tid] = l;
  }

  // ---- PV: thread -> 2 q-rows (r0, r0+8) x 4 d ----
  int r0 = tid >> 5;
  int dq = (tid & 31) * 4;
  const float* vpb =
      last ? (vbuf + (size_t)b * NS * (NHKV * ND) + kv * ND + dq)
           : (v_cache + ((size_t)b * NP + chunk * TCHUNK) * (NHKV * ND) +
              kv * ND + dq);
  float o0[4] = {0, 0, 0, 0}, o1[4] = {0, 0, 0, 0};
#pragma unroll 8
  for (int t = 0; t < tcount; ++t) {
    float4 vv = *(const float4*)(vpb + (size_t)t * (NHKV * ND));
    float p0 = p_lds[t * 17 + r0];
    float p1 = p_lds[t * 17 + r0 + 8];
    o0[0] = fmaf(p0, vv.x, o0[0]); o0[1] = fmaf(p0, vv.y, o0[1]);
    o0[2] = fmaf(p0, vv.z, o0[2]); o0[3] = fmaf(p0, vv.w, o0[3]);
    o1[0] = fmaf(p1, vv.x, o1[0]); o1[1] = fmaf(p1, vv.y, o1[1]);
    o1[2] = fmaf(p1, vv.z, o1[2]); o1[3] = fmaf(p1, vv.w, o1[3]);
  }
  size_t obase = (size_t)blk * (NQI * ND);
  *(float4*)(part_o + obase + (size_t)r0 * ND + dq) =
      make_float4(o0[0], o0[1], o0[2], o0[3]);
  *(float4*)(part_o + obase + (size_t)(r0 + 8) * ND + dq) =
      make_float4(o1[0], o1[1], o1[2], o1[3]);
}

// ---------------- combine partials -> attn_T (4096 x 32) -------------------
__global__ __launch_bounds__(256) void combine_kernel(
    const float* __restrict__ part_o, const float* __restrict__ part_m,
    const float* __restrict__ part_l, float* __restrict__ attn_T) {
  int bk = blockIdx.x;
  int tid = threadIdx.x;
  int i = tid >> 4;
  int dh = (tid & 15) * 4 + blockIdx.y * 64;
  float M = -__builtin_inff();
#pragma unroll
  for (int c = 0; c < NCHUNK; c++)
    M = fmaxf(M, part_m[((size_t)bk * NCHUNK + c) * NQI + i]);
  float L = 0.f;
  float o0 = 0.f, o1 = 0.f, o2 = 0.f, o3 = 0.f;
#pragma unroll
  for (int c = 0; c < NCHUNK; c++) {
    size_t pc = (size_t)bk * NCHUNK + c;
    float mc = part_m[pc * NQI + i];
    float w = exp2f((mc - M) * LOG2E);
    L = fmaf(part_l[pc * NQI + i], w, L);
    float4 po = *(const float4*)(part_o + pc * (NQI * ND) + (size_t)i * ND + dh);
    o0 = fmaf(w, po.x, o0);
    o1 = fmaf(w, po.y, o1);
    o2 = fmaf(w, po.z, o2);
    o3 = fmaf(w, po.w, o3);
  }
  float inv = 1.0f / L;
  int b = bk >> 3, kv = bk & 7;
  int g = i >> 2, s = i & 3;
  int h = kv * NGROUP + g;
  int r = b * NS + s;
  attn_T[(size_t)(h * ND + dh + 0) * NBS + r] = o0 * inv;
  attn_T[(size_t)(h * ND + dh + 1) * NBS + r] = o1 * inv;
  attn_T[(size_t)(h * ND + dh + 2) * NBS + r] = o2 * inv;
  attn_T[(size_t)(h * ND + dh + 3) * NBS + r] = o3 * inv;
}

// ---------------------------------------------------------------------------
extern "C" void kernel_launch(void* const* d_in, const int* in_sizes, int n_in,
                              void* d_out, int out_size, void* d_ws,
                              size_t ws_size, hipStream_t stream) {
  const float* x = (const float*)d_in[0];
  const float* wq = (const float*)d_in[1];
  const float* wk = (const float*)d_in[2];
  const float* wv = (const float*)d_in[3];
  const float* wo = (const float*)d_in[4];
  const float* cosp = (const float*)d_in[5];
  const float* sinp = (const float*)d_in[6];
  const float* k_cache = (const float*)d_in[7];
  const float* v_cache = (const float*)d_in[8];
  const int* past_len = (const int*)d_in[9];
  float* out = (float*)d_out;

  float* ws = (float*)d_ws;
  float* xT = ws;                   // 131072
  float* qb = xT + 131072;          // 131072
  float* kbuf = qb + 131072;        // 32768
  float* vbuf = kbuf + 32768;       // 32768
  float* q_t = vbuf + 32768;        // 131072
  float* k_new = q_t + 131072;      // 32768
  float* attn_T = k_new + 32768;    // 131072
  float* R = attn_T + 131072;       // shared region
  float* Pq = R;                    // 16*32*6144 = 3145728 (dead after reduce)
  float* part_o = R;                // 64*17*2048 = 2228224 (dead after combine)
  float* part_m = R + 2228224;      // 17408
  float* part_l = part_m + 17408;   // 17408
  float* Po = R;                    // 16*32*4096 = 2097152

  prep_xT<<<512, 256, 0, stream>>>(x, xT);
  gemm_part<<<dim3(48, KSPLIT), 256, 0, stream>>>(xT, wq, wk, wv, wo, Pq, 0);
  reduce_qkv<<<192, 256, 0, stream>>>(Pq, qb, kbuf, vbuf);
  rope_kernel<<<640, 256, 0, stream>>>(qb, kbuf, cosp, sinp, past_len, q_t,
                                       k_new);
  attn_kernel<<<dim3(64, NCHUNK), 256, 0, stream>>>(
      q_t, k_cache, v_cache, k_new, vbuf, part_o, part_m, part_l);
  combine_kernel<<<dim3(64, 2), 256, 0, stream>>>(part_o, part_m, part_l,
                                                  attn_T);
  gemm_part<<<dim3(32, KSPLIT), 256, 0, stream>>>(attn_T, wq, wk, wv, wo, Po,
                                                  1);
  reduce_o<<<128, 256, 0, stream>>>(Po, out);
}